// Round 2
// baseline (4553.695 us; speedup 1.0000x reference)
//
#include <hip/hip_runtime.h>
#include <hip/hip_fp16.h>
#include <math.h>

// ---------------------------------------------------------------------------
// RelationExtractionModel: B=64, T=256. Round 1: fit workspace (<=123 MB),
// fuse embed into FT GEMM, f16 xW + k-paired f16 Whh with v_dot2_f32_f16 in
// the BiLSTM recurrence. GEMMs remain fp32 VALU this round (MFMA next).
// ---------------------------------------------------------------------------

typedef _Float16 h2v __attribute__((ext_vector_type(2)));

__device__ __forceinline__ float sigm(float x) { return 1.0f / (1.0f + expf(-x)); }

struct EmbArgs {
  const float* tf; const int* pos_ids; const int* dep_ids;
  const int* e1; const int* e2; const int* sdp;
  const float* pos_tab; const float* dep_tab; const float* dist_tab;
  const float* sdp_tab;
};

// ---------------- generic fp32 GEMM: C[M,N] = act(A[M,K] @ B[K,N] + bias) ---
// a_mode 0: dense A (lda)
// a_mode 1: banded rows of h_buf[B,256,256]: b=r>>band_log2, t=band_lo+(r&mask)
// a_mode 2: parent-sum rows: p=band_lo+(r&mask); row = h[b,2p]+h[b,2p+1]
//           (child 2p dropped when 2p==0: root self-loop)
// a_mode 3: fused embedding row gather (k<768 tf, then pos/dep/d1/d2/sdp)
// epi 0: +bias; epi 1: tanh(+bias); epi 2: sigmoid(acc + xWf[b,head]) *
//           c_buf[b,t] * (head!=t), rows banded as a_mode 1.
// out_half: store f16 instead of f32.
__global__ __launch_bounds__(256) void k_gemm(
    const float* __restrict__ A, const float* __restrict__ Bm,
    const float* __restrict__ bias, void* __restrict__ Cv,
    int M, int N, int K, int lda,
    int a_mode, int band_lo, int band_log2,
    int epi_mode, int out_half,
    const int* __restrict__ dep_heads,
    const float* __restrict__ xWf, const float* __restrict__ c_buf,
    EmbArgs ea) {
  __shared__ float As[16][132];
  __shared__ float Bs[16][132];
  int tid = threadIdx.x;
  int col0 = blockIdx.x * 128;
  int row0 = blockIdx.y * 128;
  int tx = tid & 15, ty = tid >> 4;
  float acc[8][8];
#pragma unroll
  for (int i = 0; i < 8; ++i)
#pragma unroll
    for (int j = 0; j < 8; ++j) acc[i][j] = 0.0f;

  int bmask = (1 << band_log2) - 1;
  for (int kt = 0; kt < K; kt += 16) {
    // ---- A tile 128x16
#pragma unroll
    for (int i = 0; i < 2; ++i) {
      int lin = tid + i * 256;
      int r = lin >> 2, c4 = (lin & 3) * 4;
      int row = row0 + r;
      float4 v = {0.0f, 0.0f, 0.0f, 0.0f};
      if (row < M) {
        if (a_mode == 0) {
          v = *(const float4*)(A + (size_t)row * lda + kt + c4);
        } else if (a_mode == 1) {
          int b_ = row >> band_log2;
          int t_ = band_lo + (row & bmask);
          v = *(const float4*)(A + (size_t)((b_ << 8) + t_) * 256 + kt + c4);
        } else if (a_mode == 2) {
          int b_ = row >> band_log2;
          int p_ = band_lo + (row & bmask);
          const float* p0 = A + (size_t)((b_ << 8) + 2 * p_) * 256 + kt + c4;
          float4 x0 = {0.0f, 0.0f, 0.0f, 0.0f};
          if (2 * p_ != 0) x0 = *(const float4*)p0;
          float4 x1 = *(const float4*)(p0 + 256);
          v.x = x0.x + x1.x; v.y = x0.y + x1.y;
          v.z = x0.z + x1.z; v.w = x0.w + x1.w;
        } else {  // a_mode 3: fused embed, K=912
          int k0 = kt + c4;
          if (k0 < 768) {
            v = *(const float4*)(ea.tf + (size_t)row * 768 + k0);
          } else {
            int b_ = row >> 8, t_ = row & 255;
            const float* src; int off;
            if (k0 < 800) { src = ea.pos_tab + ea.pos_ids[row] * 32; off = k0 - 768; }
            else if (k0 < 832) { src = ea.dep_tab + ea.dep_ids[row] * 32; off = k0 - 800; }
            else if (k0 < 864) {
              int d = t_ - ea.e1[b_] + 10; d = d < 0 ? 0 : (d > 20 ? 20 : d);
              src = ea.dist_tab + d * 32; off = k0 - 832;
            } else if (k0 < 896) {
              int d = t_ - ea.e2[b_] + 10; d = d < 0 ? 0 : (d > 20 ? 20 : d);
              src = ea.dist_tab + d * 32; off = k0 - 864;
            } else { src = ea.sdp_tab + ea.sdp[row] * 16; off = k0 - 896; }
            v.x = src[off]; v.y = src[off + 1]; v.z = src[off + 2]; v.w = src[off + 3];
          }
        }
      }
      As[c4 + 0][r] = v.x; As[c4 + 1][r] = v.y;
      As[c4 + 2][r] = v.z; As[c4 + 3][r] = v.w;
    }
    // ---- B tile 16x128 (N mult of 128 or grid sized so cols in range)
#pragma unroll
    for (int i = 0; i < 2; ++i) {
      int lin = tid + i * 256;
      int kr = lin >> 5, c4 = (lin & 31) * 4;
      float4 v = *(const float4*)(Bm + (size_t)(kt + kr) * N + col0 + c4);
      *(float4*)&Bs[kr][c4] = v;
    }
    __syncthreads();
#pragma unroll
    for (int kk = 0; kk < 16; ++kk) {
      float a[8], bb[8];
      *(float4*)&a[0] = *(const float4*)&As[kk][ty * 8];
      *(float4*)&a[4] = *(const float4*)&As[kk][ty * 8 + 4];
      *(float4*)&bb[0] = *(const float4*)&Bs[kk][tx * 8];
      *(float4*)&bb[4] = *(const float4*)&Bs[kk][tx * 8 + 4];
#pragma unroll
      for (int i = 0; i < 8; ++i)
#pragma unroll
        for (int j = 0; j < 8; ++j) acc[i][j] += a[i] * bb[j];
    }
    __syncthreads();
  }

#pragma unroll
  for (int i = 0; i < 8; ++i) {
    int row = row0 + ty * 8 + i;
    if (row >= M) continue;
    int b_ = 0, t_ = 0, par = 0;
    float m = 1.0f;
    if (epi_mode == 2) {
      b_ = row >> band_log2;
      t_ = band_lo + (row & bmask);
      par = dep_heads[(b_ << 8) + t_];
      m = (par != t_) ? 1.0f : 0.0f;
    }
    float vv[8];
#pragma unroll
    for (int j = 0; j < 8; ++j) {
      int col = col0 + tx * 8 + j;
      float v = acc[i][j];
      if (bias) v += bias[col];
      if (epi_mode == 1) {
        v = tanhf(v);
      } else if (epi_mode == 2) {
        float xwv = xWf[(size_t)((b_ << 8) + par) * 256 + col];
        float cv = c_buf[(size_t)((b_ << 8) + t_) * 256 + col];
        v = sigm(v + xwv) * cv * m;
      }
      vv[j] = v;
    }
    if (out_half) {
      union { __half h[8]; float4 f4; } pk;
#pragma unroll
      for (int j = 0; j < 8; ++j) pk.h[j] = __float2half_rn(vv[j]);
      *(float4*)((__half*)Cv + (size_t)row * N + col0 + tx * 8) = pk.f4;
    } else {
      float* cp = (float*)Cv + (size_t)row * N + col0 + tx * 8;
      *(float4*)cp = *(float4*)&vv[0];
      *(float4*)(cp + 4) = *(float4*)&vv[4];
    }
  }
}

// ---------------- pack Whh[256,1024] f32 -> [128][1024] half2 (k-paired) ----
__global__ __launch_bounds__(256) void k_packWhh(const float* __restrict__ W,
                                                 __half2* __restrict__ P) {
  int i = blockIdx.x * 256 + threadIdx.x;  // 0..131071
  int kk = i >> 10, col = i & 1023;
  P[i] = __halves2half2(__float2half_rn(W[(size_t)(2 * kk) * 1024 + col]),
                        __float2half_rn(W[(size_t)(2 * kk + 1) * 1024 + col]));
}

// ---------------- BiLSTM recurrence (f16 xW, k-paired f16 Whh, fdot2) -------
// 64 blocks: dir=bx&1, pair=bx>>1; 512 threads = 2 batches x 256.
__global__ __launch_bounds__(512) void k_lstm(
    const __half* __restrict__ xW_f, const __half* __restrict__ xW_b,
    const __half2* __restrict__ WPf, const __half2* __restrict__ WPb,
    float* __restrict__ x_tree) {
  int bx = blockIdx.x;
  int dir = bx & 1, pair = bx >> 1;
  int tid = threadIdx.x;
  int bl = tid >> 8, u = tid & 255;
  int colbase = (u >> 6) * 256 + (u & 63) * 4;
  int b = pair * 2 + bl;
  const __half* xW = dir ? xW_b : xW_f;
  const __half2* WP = dir ? WPb : WPf;
  __shared__ __half h_sh[2][256];
  __shared__ float g_sh[2][1024];
  h_sh[bl][u] = __float2half_rn(0.0f);
  float cst = 0.0f;
  __syncthreads();
  for (int s = 0; s < 256; ++s) {
    int t = dir ? (255 - s) : s;
    const __half* xr = xW + (size_t)((b << 8) + t) * 1024 + colbase;
    float4 acc;
    {
      __half2 x01 = *(const __half2*)xr;
      __half2 x23 = *(const __half2*)(xr + 2);
      float2 a01 = __half22float2(x01), a23 = __half22float2(x23);
      acc.x = a01.x; acc.y = a01.y; acc.z = a23.x; acc.w = a23.y;
    }
    const h2v* hrow = (const h2v*)&h_sh[bl][0];
#pragma unroll 8
    for (int kk = 0; kk < 128; ++kk) {
      h2v hk = hrow[kk];
      float4 wraw = *(const float4*)(WP + (size_t)kk * 1024 + colbase);
      const h2v* w = (const h2v*)&wraw;
      acc.x = __builtin_amdgcn_fdot2(hk, w[0], acc.x, false);
      acc.y = __builtin_amdgcn_fdot2(hk, w[1], acc.y, false);
      acc.z = __builtin_amdgcn_fdot2(hk, w[2], acc.z, false);
      acc.w = __builtin_amdgcn_fdot2(hk, w[3], acc.w, false);
    }
    *(float4*)&g_sh[bl][colbase] = acc;
    __syncthreads();
    float gi = g_sh[bl][u];
    float gf = g_sh[bl][256 + u];
    float gg = g_sh[bl][512 + u];
    float go = g_sh[bl][768 + u];
    cst = sigm(gf) * cst + sigm(gi) * tanhf(gg);
    float hn = sigm(go) * tanhf(cst);
    x_tree[(size_t)((b << 8) + t) * 544 + dir * 256 + u] = hn;
    h_sh[bl][u] = __float2half_rn(hn);
    __syncthreads();
  }
}

// ---------------- fill dep_emb into x_tree cols [512,544) ----------------
__global__ __launch_bounds__(256) void k_depfill(
    const int* __restrict__ dep_ids, const float* __restrict__ dep_tab,
    float* __restrict__ x_tree) {
  int e = blockIdx.x * 256 + threadIdx.x;  // 0..524287
  int row = e >> 5, k = e & 31;
  x_tree[(size_t)row * 544 + 512 + k] = dep_tab[dep_ids[row] * 32 + k];
}

// ---------------- tree leaves: t in [128,256) ----------------
__global__ __launch_bounds__(256) void k_leaves(
    const float* __restrict__ xWiou, float* __restrict__ h_buf,
    float* __restrict__ c_buf) {
  int r = blockIdx.x;  // 0..8191
  int b = r >> 7, t = 128 + (r & 127);
  size_t row = (size_t)((b << 8) + t);
  int j = threadIdx.x;
  float i = xWiou[row * 768 + j];
  float o = xWiou[row * 768 + 256 + j];
  float u = xWiou[row * 768 + 512 + j];
  float c = sigm(i) * tanhf(u);
  float h = sigm(o) * tanhf(c);
  c_buf[row * 256 + j] = c;
  h_buf[row * 256 + j] = h;
}

// ---------------- tree stage update ----------------
__global__ __launch_bounds__(256) void k_update(
    const float* __restrict__ xWiou, const float* __restrict__ iou_lin,
    const float* __restrict__ FC, float* __restrict__ h_buf,
    float* __restrict__ c_buf, int plo, int nplog2) {
  int r = blockIdx.x, j = threadIdx.x;
  int npm = (1 << nplog2) - 1;
  int b = r >> nplog2, loc = r & npm, p = plo + loc;
  size_t row = (size_t)((b << 8) + p);
  float i = xWiou[row * 768 + j] + iou_lin[(size_t)r * 768 + j];
  float o = xWiou[row * 768 + 256 + j] + iou_lin[(size_t)r * 768 + 256 + j];
  float u = xWiou[row * 768 + 512 + j] + iou_lin[(size_t)r * 768 + 512 + j];
  int nch = 2 << nplog2;
  float fc = FC[(size_t)(b * nch + 2 * loc) * 256 + j] +
             FC[(size_t)(b * nch + 2 * loc + 1) * 256 + j];
  float c = sigm(i) * tanhf(u) + fc;
  float h = sigm(o) * tanhf(c);
  c_buf[row * 256 + j] = c;
  h_buf[row * 256 + j] = h;
}

// ---------------- classifier ----------------
__global__ __launch_bounds__(256) void k_classifier(
    const float* __restrict__ h_buf, const int* __restrict__ root_idx,
    const float* __restrict__ W1, const float* __restrict__ b1,
    const float* __restrict__ W2, const float* __restrict__ b2,
    float* __restrict__ out) {
  int b = blockIdx.x, j = threadIdx.x;
  __shared__ float hroot[256];
  __shared__ float hid[256];
  int root = root_idx[b];
  hroot[j] = h_buf[(size_t)((b << 8) + root) * 256 + j];
  __syncthreads();
  float acc = b1[j];
  for (int k = 0; k < 256; ++k) acc += hroot[k] * W1[k * 256 + j];
  hid[j] = fmaxf(acc, 0.0f);
  __syncthreads();
  if (j < 10) {
    float o = b2[j];
    for (int k = 0; k < 256; ++k) o += hid[k] * W2[k * 10 + j];
    out[b * 10 + j] = o;
  }
}

// ---------------------------------------------------------------------------
extern "C" void kernel_launch(void* const* d_in, const int* in_sizes, int n_in,
                              void* d_out, int out_size, void* d_ws,
                              size_t ws_size, hipStream_t stream) {
  (void)in_sizes; (void)n_in; (void)out_size; (void)ws_size;
  const float* tf       = (const float*)d_in[0];
  const int*   pos_ids  = (const int*)d_in[1];
  const int*   dep_ids  = (const int*)d_in[2];
  const int*   e1       = (const int*)d_in[3];
  const int*   e2       = (const int*)d_in[4];
  const int*   sdp      = (const int*)d_in[5];
  const int*   heads    = (const int*)d_in[6];
  const int*   root     = (const int*)d_in[7];
  const float* pos_tab  = (const float*)d_in[8];
  const float* dep_tab  = (const float*)d_in[9];
  const float* dist_tab = (const float*)d_in[10];
  const float* sdp_tab  = (const float*)d_in[11];
  const float* W_ft     = (const float*)d_in[12];
  const float* b_ft     = (const float*)d_in[13];
  const float* Wih_f    = (const float*)d_in[14];
  const float* Whh_f    = (const float*)d_in[15];
  const float* bl_f     = (const float*)d_in[16];
  const float* Wih_b    = (const float*)d_in[17];
  const float* Whh_b    = (const float*)d_in[18];
  const float* bl_b     = (const float*)d_in[19];
  const float* W_iou    = (const float*)d_in[20];
  const float* U_iou    = (const float*)d_in[21];
  const float* b_iou    = (const float*)d_in[22];
  const float* Wf_t     = (const float*)d_in[23];
  const float* Uf_t     = (const float*)d_in[24];
  const float* bf_t     = (const float*)d_in[25];
  const float* W1       = (const float*)d_in[26];
  const float* b1       = (const float*)d_in[27];
  const float* W2       = (const float*)d_in[28];
  const float* b2       = (const float*)d_in[29];

  // ---- workspace layout, lifetime-overlaid; peak 122,683,392 B (~117 MiB)
  char* ws = (char*)d_ws;
  __half*  XFh   = (__half*)(ws + 0ull);          // 33.5 MB  live: xW gemm -> lstm
  __half*  XBh   = (__half*)(ws + 33554432ull);   // 33.5 MB  live: xW gemm -> lstm
  float*   T     = (float*)(ws + 67108864ull);    // 33.5 MB  live: FT -> xW gemms
  float*   XT    = (float*)(ws + 67108864ull);    // 35.7 MB  live: lstm -> iou/f gemms (over T)
  float*   XWIOU = (float*)(ws + 0ull);           // 50.3 MB  live: after lstm (over XFh/XBh)
  float*   XWF   = (float*)(ws + 50331648ull);    // 16.8 MB  (over XBh)
  float*   H     = (float*)(ws + 67108864ull);    // 16.8 MB  live: tree (over XT)
  float*   C     = (float*)(ws + 83886080ull);    // 16.8 MB
  float*   FCb   = (float*)(ws + 100663296ull);   //  8.4 MB
  float*   IOUL  = (float*)(ws + 109051904ull);   // 12.6 MB
  __half2* WPf   = (__half2*)(ws + 121634816ull); //  0.5 MB
  __half2* WPb   = (__half2*)(ws + 122159104ull); //  0.5 MB -> end 122,683,392

  EmbArgs ea{tf, pos_ids, dep_ids, e1, e2, sdp, pos_tab, dep_tab, dist_tab, sdp_tab};

  // 0. pack Whh to k-paired f16
  k_packWhh<<<dim3(512), dim3(256), 0, stream>>>(Whh_f, WPf);
  k_packWhh<<<dim3(512), dim3(256), 0, stream>>>(Whh_b, WPb);
  // 1. transformed = tanh(embed_concat @ W_ft + b_ft)   (embed fused in A-load)
  k_gemm<<<dim3(4, 128), dim3(256), 0, stream>>>(
      nullptr, W_ft, b_ft, (void*)T, 16384, 512, 912, 0,
      3, 0, 0, 1, 0, nullptr, nullptr, nullptr, ea);
  // 2. xW_f / xW_b (f16 out)
  k_gemm<<<dim3(8, 128), dim3(256), 0, stream>>>(
      T, Wih_f, bl_f, (void*)XFh, 16384, 1024, 512, 512,
      0, 0, 0, 0, 1, nullptr, nullptr, nullptr, ea);
  k_gemm<<<dim3(8, 128), dim3(256), 0, stream>>>(
      T, Wih_b, bl_b, (void*)XBh, 16384, 1024, 512, 512,
      0, 0, 0, 0, 1, nullptr, nullptr, nullptr, ea);
  // 3. BiLSTM recurrence -> x_tree cols [0,512)
  k_lstm<<<dim3(64), dim3(512), 0, stream>>>(XFh, XBh, WPf, WPb, XT);
  // 4. dep_emb -> x_tree cols [512,544)
  k_depfill<<<dim3(2048), dim3(256), 0, stream>>>(dep_ids, dep_tab, XT);
  // 5. xWiou / xWf
  k_gemm<<<dim3(6, 128), dim3(256), 0, stream>>>(
      XT, W_iou, b_iou, (void*)XWIOU, 16384, 768, 544, 544,
      0, 0, 0, 0, 0, nullptr, nullptr, nullptr, ea);
  k_gemm<<<dim3(2, 128), dim3(256), 0, stream>>>(
      XT, Wf_t, bf_t, (void*)XWF, 16384, 256, 544, 544,
      0, 0, 0, 0, 0, nullptr, nullptr, nullptr, ea);
  // 6. tree: leaves then levels bottom-up (exact vs 9 dense sweeps)
  k_leaves<<<dim3(8192), dim3(256), 0, stream>>>(XWIOU, H, C);
  const int plos[8] = {64, 32, 16, 8, 4, 2, 1, 0};
  const int lgs[8]  = {6, 5, 4, 3, 2, 1, 0, 0};
  for (int s = 0; s < 8; ++s) {
    int plo = plos[s], lg = lgs[s];
    int npar = 1 << lg;
    int Mch = 64 * 2 * npar;
    int Mp = 64 * npar;
    // FC[child] = sigmoid(h_child @ Uf + xWf[parent]) * c_child * mask
    k_gemm<<<dim3(2, (Mch + 127) / 128), dim3(256), 0, stream>>>(
        H, Uf_t, nullptr, (void*)FCb, Mch, 256, 256, 0,
        1, 2 * plo, lg + 1, 2, 0, heads, XWF, C, ea);
    // iou_lin = (h[2p]+h[2p+1]) @ U_iou
    k_gemm<<<dim3(6, (Mp + 127) / 128), dim3(256), 0, stream>>>(
        H, U_iou, nullptr, (void*)IOUL, Mp, 768, 256, 0,
        2, plo, lg, 0, 0, nullptr, nullptr, nullptr, ea);
    k_update<<<dim3(Mp), dim3(256), 0, stream>>>(XWIOU, IOUL, FCb, H, C, plo, lg);
  }
  // 7. classifier
  k_classifier<<<dim3(64), dim3(256), 0, stream>>>(H, root, W1, b1, W2, b2,
                                                   (float*)d_out);
}